// Round 7
// baseline (489.977 us; speedup 1.0000x reference)
//
#include <hip/hip_runtime.h>
#include <math.h>

// Problem constants
#define B_    8
#define L_    512
#define K_    16
#define E_    32
#define NH_   64
#define WOFF_ 1

// Workspace layout (floats):
//   qmat  [B][L][32]   @ 0        (131072)
//   kmatT [B][32][L]   @ 131072   (131072)
//   (att no longer materialized — fused into k_attn_gi)
//   gi    [B][L][192]  @ 524288   (786432)

typedef float v2f __attribute__((ext_vector_type(2)));
typedef float v4f __attribute__((ext_vector_type(4)));

// ---------------------------------------------------------------------------
// Kernel 1: key_emb -> q, k projections. One thread per (b,l).
// ---------------------------------------------------------------------------
__global__ __launch_bounds__(256) void k_embed(
    const float* __restrict__ ts, const float* __restrict__ Wl,
    const float* __restrict__ bl, const float* __restrict__ Wp,
    const float* __restrict__ bp, const float* __restrict__ Wq,
    const float* __restrict__ bq, const float* __restrict__ Wk,
    const float* __restrict__ bk,
    float* __restrict__ qmat, float* __restrict__ kmatT)
{
    __shared__ float WqL[1024], WkL[1024];
    __shared__ float bqL[32], bkL[32], WpL[31], bpL[31];
    __shared__ float wl0, bl0;
    const int tid = threadIdx.x;

    {
        float4 v = ((const float4*)Wq)[tid];
        ((float4*)WqL)[tid] = v;
        float4 u = ((const float4*)Wk)[tid];
        ((float4*)WkL)[tid] = u;
    }
    if (tid < 32) { bqL[tid] = bq[tid]; bkL[tid] = bk[tid]; }
    if (tid < 31) { WpL[tid] = Wp[tid]; bpL[tid] = bp[tid]; }
    if (tid == 0) { wl0 = Wl[0]; bl0 = bl[0]; }
    __syncthreads();

    const int p = blockIdx.x * 256 + tid;      // 0..4095
    const float t = ts[p];
    float e[32];
    e[0] = t * wl0 + bl0;
    #pragma unroll
    for (int j = 1; j < 32; ++j) e[j] = sinf(t * WpL[j - 1] + bpL[j - 1]);

    const int b = p >> 9, l = p & 511;
    float4* qm4 = (float4*)(qmat + (size_t)p * 32);
    float*  kT  = kmatT + (size_t)b * 32 * 512 + l;

    for (int dq = 0; dq < 8; ++dq) {
        float q0 = bqL[4*dq+0], q1 = bqL[4*dq+1], q2 = bqL[4*dq+2], q3 = bqL[4*dq+3];
        float k0 = bkL[4*dq+0], k1 = bkL[4*dq+1], k2 = bkL[4*dq+2], k3 = bkL[4*dq+3];
        const float* wq = &WqL[(4*dq) * 32];
        const float* wk = &WkL[(4*dq) * 32];
        #pragma unroll
        for (int j = 0; j < 32; ++j) {
            const float ej = e[j];
            q0 = fmaf(wq[j],      ej, q0);
            q1 = fmaf(wq[32 + j], ej, q1);
            q2 = fmaf(wq[64 + j], ej, q2);
            q3 = fmaf(wq[96 + j], ej, q3);
            k0 = fmaf(wk[j],      ej, k0);
            k1 = fmaf(wk[32 + j], ej, k1);
            k2 = fmaf(wk[64 + j], ej, k2);
            k3 = fmaf(wk[96 + j], ej, k3);
        }
        qm4[dq] = make_float4(q0, q1, q2, q3);
        kT[(4*dq + 0) * 512] = k0;
        kT[(4*dq + 1) * 512] = k1;
        kT[(4*dq + 2) * 512] = k2;
        kT[(4*dq + 3) * 512] = k3;
    }
}

// ---------------------------------------------------------------------------
// Kernel 2 (FUSED attn + gi): per-(b,qb) attention -> att rows in LDS ->
// gi = att @ W_ih^T + b_ih written directly.  grid (32 qb, 8 b), 256 thr.
//
// Fusion correctness: k_attn block (qb,b) produces exactly rows
// [qb*16, qb*16+16) of batch b — the same 16 flattened rows that old
// k_gi block bid = b*32+qb consumed. att values pass through LDS as fp32
// (bit-identical to the old global roundtrip); the gi compute/order is
// copied verbatim from k_gi. Saves one launch + 1 MB att write/read.
// ---------------------------------------------------------------------------
__global__ __launch_bounds__(256) void k_attn_gi(
    const float* __restrict__ qmat, const float* __restrict__ kmatT,
    const float* __restrict__ val,  const int*   __restrict__ mark,
    const float* __restrict__ npm,  const float* __restrict__ Wo,
    const float* __restrict__ bo,   const float* __restrict__ Wih,
    const float* __restrict__ bih,  float* __restrict__ gi)
{
    __shared__ float srow[4 * 512];   // per-wave score row
    __shared__ int   cc[512];         // category (-1 if padded)
    __shared__ float vv[512];         // values
    __shared__ float WL[192 * 65];    // W_ih staged (padded rows)
    __shared__ float bL[192];
    __shared__ float attL[16 * 64];   // the 16 att rows this block owns
    const int tid = threadIdx.x;
    const int qb  = blockIdx.x;       // 0..31
    const int b   = blockIdx.y;       // 0..7

    for (int k = tid; k < 512; k += 256) {
        const int   m  = mark[b * 512 + k];
        const float np = npm[b * 512 + k];
        cc[k] = (np > 0.0f) ? (m - 1) : -1;
        vv[k] = val[b * 512 + k];
    }
    // stage W_ih (verbatim from old k_gi)
    for (int idx = tid; idx < 3072; idx += 256) {
        float4 v = ((const float4*)Wih)[idx];
        const int g = idx >> 4, jq = idx & 15;
        float* dst = &WL[g * 65 + jq * 4];
        dst[0] = v.x; dst[1] = v.y; dst[2] = v.z; dst[3] = v.w;
    }
    if (tid < 192) bL[tid] = bih[tid];
    __syncthreads();

    const int w = tid >> 6, lane = tid & 63;
    const float* kTb = kmatT + (size_t)b * 32 * 512;

    for (int iq = 0; iq < 4; ++iq) {
        const int q = qb * 16 + w * 4 + iq;

        float qr[32];
        const float4* qm4 = (const float4*)(qmat + (size_t)(b * 512 + q) * 32);
        #pragma unroll
        for (int j4 = 0; j4 < 8; ++j4) {
            float4 v = qm4[j4];
            qr[4*j4+0] = v.x; qr[4*j4+1] = v.y; qr[4*j4+2] = v.z; qr[4*j4+3] = v.w;
        }

        float acc[8];
        #pragma unroll
        for (int m = 0; m < 8; ++m) acc[m] = 0.0f;
        #pragma unroll 4
        for (int j = 0; j < 32; ++j) {
            const float* row = kTb + j * 512 + lane;
            const float  qj  = qr[j];
            #pragma unroll
            for (int m = 0; m < 8; ++m) acc[m] = fmaf(qj, row[m * 64], acc[m]);
        }
        #pragma unroll
        for (int m = 0; m < 8; ++m)
            srow[w * 512 + m * 64 + lane] = acc[m] * 0.17677669529663687f;
        __syncthreads();

        const int c = lane & 15, s = lane >> 4;
        float mx = -1e30f, Z = 0.0f, X = 0.0f;
        const int base = s * 128;
        for (int t = 0; t < 128; ++t) {
            const int k = base + ((t + s) & 127);
            if (cc[k] == c) {
                const float l  = (k <= q + WOFF_) ? srow[w * 512 + k] : 0.0f;
                const float mn = fmaxf(mx, l);
                const float e1 = __expf(l - mn);
                const float sc = __expf(mx - mn);
                Z = Z * sc + e1;
                X = X * sc + e1 * vv[k];
                mx = mn;
            }
        }
        #pragma unroll
        for (int off = 16; off <= 32; off <<= 1) {
            const float mo = __shfl_xor(mx, off);
            const float Zo = __shfl_xor(Z, off);
            const float Xo = __shfl_xor(X, off);
            const float mn = fmaxf(mx, mo);
            const float a0 = __expf(mx - mn);
            const float a1 = __expf(mo - mn);
            Z = Z * a0 + Zo * a1;
            X = X * a0 + Xo * a1;
            mx = mn;
        }
        const float x = (Z > 0.0f) ? X / Z : 0.0f;

        float xs[16];
        #pragma unroll
        for (int c2 = 0; c2 < 16; ++c2) xs[c2] = __shfl(x, c2);

        const float4* wo4 = (const float4*)(Wo + lane * 16);
        float a = bo[lane];
        #pragma unroll
        for (int c4 = 0; c4 < 4; ++c4) {
            float4 v = wo4[c4];
            a += xs[4*c4+0] * v.x + xs[4*c4+1] * v.y + xs[4*c4+2] * v.z + xs[4*c4+3] * v.w;
        }
        attL[(w * 4 + iq) * 64 + lane] = a;   // row stays in LDS
        __syncthreads();
    }
    // final barrier of the iq loop makes all 16 attL rows visible

    // ---- gi part (verbatim from old k_gi; arow now reads attL) ----
    const size_t out0 = (size_t)(b * 32 + qb) * 16 * 192;
    for (int pp = 0; pp < 12; ++pp) {
        const int p = tid + 256 * pp;
        const int r = p / 192, g = p - r * 192;
        float a0 = bL[g], a1 = 0.f, a2 = 0.f, a3 = 0.f;
        const float* wrow = &WL[g * 65];
        const float* arow = &attL[r * 64];
        #pragma unroll
        for (int j = 0; j < 64; j += 4) {
            a0 = fmaf(arow[j + 0], wrow[j + 0], a0);
            a1 = fmaf(arow[j + 1], wrow[j + 1], a1);
            a2 = fmaf(arow[j + 2], wrow[j + 2], a2);
            a3 = fmaf(arow[j + 3], wrow[j + 3], a3);
        }
        gi[out0 + p] = (a0 + a1) + (a2 + a3);
    }
}

// ---------------------------------------------------------------------------
// Kernel 4: sequential GRU — 8 batches as 8 WAVES in ONE block (one CU).
//
// r6 post-mortem: per-wave budget bracketed at ~500 VALU + ~320 stall
// cy/step; single-wave-per-SIMD leaves the stall fully exposed (8 blocks
// on 8 different CUs). The stall (ds_write->broadcast-read roundtrip +
// TRANS tail chain) is exactly what HW multi-wave scheduling hides.
// Fix: <<<1, 512>>> — waves map round-robin to the 4 SIMDs => 2 waves per
// SIMD; the issue arbiter fills wave A's stalls with wave B's VALU work.
// No barriers, per-wave hs slice, inner loop byte-identical to r6.
// (r2's "2 chains in 1 wave" failed because it doubled the ISSUE stream;
// 2 WAVES share nothing but the SIMD's issue port.)
// ---------------------------------------------------------------------------

#define GRU_STEP(u, DO_REFILL) {                                           \
    v4f hv[16];                                                            \
    /* prologue: issue 6 chunks ahead */                                   \
    _Pragma("unroll")                                                      \
    for (int k = 0; k < 6; ++k) hv[k] = hs4[k];                            \
    const float gr = pr[u], gz = pz[u], gn = pn[u];                        \
    if (DO_REFILL) {                                                       \
        pr[u] = pf[0];                                                     \
        pz[u] = pf[64];                                                    \
        pn[u] = pf[128];                                                   \
        pf += 192;                                                         \
    }                                                                      \
    v2f ar2 = {gr + br, 0.0f};                                             \
    v2f az2 = {gz + bz, 0.0f};                                             \
    v2f an2 = {bn, 0.0f};                                                  \
    _Pragma("unroll")                                                      \
    for (int k = 0; k < 16; ++k) {                                         \
        if (k < 10) hv[k + 6] = hs4[k + 6];   /* stay 6 ahead */           \
        v2f p0 = __builtin_shufflevector(hv[k], hv[k], 0, 1);              \
        v2f p1 = __builtin_shufflevector(hv[k], hv[k], 2, 3);              \
        ar2 = wr[2*k]     * p0 + ar2;   /* v_pk_fma_f32 */                 \
        az2 = wz[2*k]     * p0 + az2;                                      \
        an2 = wn[2*k]     * p0 + an2;                                      \
        ar2 = wr[2*k + 1] * p1 + ar2;                                      \
        az2 = wz[2*k + 1] * p1 + az2;                                      \
        an2 = wn[2*k + 1] * p1 + an2;                                      \
    }                                                                      \
    const float ar = ar2.x + ar2.y;                                        \
    const float az = az2.x + az2.y;                                        \
    const float hn = an2.x + an2.y;                                        \
    const float r = __builtin_amdgcn_rcpf(1.0f + __expf(-ar));             \
    const float z = __builtin_amdgcn_rcpf(1.0f + __expf(-az));             \
    float npre = gn + r * hn;                                              \
    npre = fminf(fmaxf(npre, -15.0f), 15.0f);                              \
    const float e2 = __expf(2.0f * npre);                                  \
    const float n  = (e2 - 1.0f) * __builtin_amdgcn_rcpf(e2 + 1.0f);       \
    h = fmaf(z, h - n, n);            /* (1-z)*n + z*h */                  \
    hsw[lane] = h;                    /* next step's broadcast source */   \
    *outp = h;                        /* fire-and-forget */                \
    outp += 64;                                                            \
}

__global__ __launch_bounds__(512, 2) void k_gru(
    const float* __restrict__ gi, const float* __restrict__ Whh,
    const float* __restrict__ bhh, float* __restrict__ out)
{
    __shared__ float hs[512];         // 8 waves x 64
    const int tid  = threadIdx.x;
    const int lane = tid & 63;        // 0..63
    const int b    = tid >> 6;        // wave id == batch 0..7

    float* hsw = hs + (b << 6);       // this wave's private slice

    // Stage this lane's three W_hh rows into registers (as 32 x v2f each).
    v2f wr[32], wz[32], wn[32];
    {
        const v2f* r2 = (const v2f*)(Whh + (size_t)lane * 64);
        const v2f* z2 = (const v2f*)(Whh + (size_t)(lane + 64) * 64);
        const v2f* n2 = (const v2f*)(Whh + (size_t)(lane + 128) * 64);
        #pragma unroll
        for (int j = 0; j < 32; ++j) {
            wr[j] = r2[j];
            wz[j] = z2[j];
            wn[j] = n2[j];
        }
    }
    const float br = bhh[lane];
    const float bz = bhh[lane + 64];
    const float bn = bhh[lane + 128];

    const float* gib  = gi  + (size_t)b * 512 * 192;
    float*       outp = out + (size_t)b * 512 * 64 + lane;

    float h = 0.0f;
    hsw[lane] = 0.0f;                 // h_{-1} = 0 (same wave; DS in-order)

    // 2-deep gi prefetch ring
    float pr[2], pz[2], pn[2];
    #pragma unroll
    for (int i = 0; i < 2; ++i) {
        const float* gp = gib + (size_t)i * 192;
        pr[i] = gp[lane];
        pz[i] = gp[lane + 64];
        pn[i] = gp[lane + 128];
    }
    // refill pointer: lane offset baked in, advanced +192 per step
    const float* pf = gib + (size_t)2 * 192 + lane;

    const v4f* hs4 = (const v4f*)hsw;

    // main loop: 255 groups of 2, steps 0..509, refills rows 2..511
    for (int tt = 0; tt < 510; tt += 2) {
        GRU_STEP(0, 1)
        GRU_STEP(1, 1)
    }
    // epilogue: steps 510..511 from the ring, no refill
    GRU_STEP(0, 0)
    GRU_STEP(1, 0)
}

// ---------------------------------------------------------------------------
extern "C" void kernel_launch(void* const* d_in, const int* in_sizes, int n_in,
                              void* d_out, int out_size, void* d_ws, size_t ws_size,
                              hipStream_t stream)
{
    const float* ts   = (const float*)d_in[0];
    const float* val  = (const float*)d_in[1];
    const int*   mark = (const int*)  d_in[2];
    const float* npm  = (const float*)d_in[3];
    const float* Wl   = (const float*)d_in[4];
    const float* bl   = (const float*)d_in[5];
    const float* Wp   = (const float*)d_in[6];
    const float* bp   = (const float*)d_in[7];
    const float* Wq   = (const float*)d_in[8];
    const float* bq   = (const float*)d_in[9];
    const float* Wk   = (const float*)d_in[10];
    const float* bk   = (const float*)d_in[11];
    const float* Wo   = (const float*)d_in[12];
    const float* bo   = (const float*)d_in[13];
    const float* Wih  = (const float*)d_in[14];
    const float* Whh  = (const float*)d_in[15];
    const float* bih  = (const float*)d_in[16];
    const float* bhh  = (const float*)d_in[17];

    float* ws    = (float*)d_ws;
    float* qmat  = ws;                 // 131072
    float* kmatT = ws + 131072;        // 131072
    float* gi    = ws + 524288;        // 786432
    float* out   = (float*)d_out;

    k_embed<<<16, 256, 0, stream>>>(ts, Wl, bl, Wp, bp, Wq, bq, Wk, bk, qmat, kmatT);
    k_attn_gi<<<dim3(32, 8), 256, 0, stream>>>(qmat, kmatT, val, mark, npm, Wo, bo, Wih, bih, gi);
    k_gru<<<1, 512, 0, stream>>>(gi, Whh, bhh, out);
}

// Round 8
// 380.107 us; speedup vs baseline: 1.2891x; 1.2891x over previous
//
#include <hip/hip_runtime.h>
#include <math.h>

// Problem constants
#define B_    8
#define L_    512
#define K_    16
#define E_    32
#define NH_   64
#define WOFF_ 1

// Workspace layout (floats):
//   qmat  [B][L][32]   @ 0        (131072)
//   kmatT [B][32][L]   @ 131072   (131072)
//   (att not materialized — fused into k_attn_gi)
//   gi    [B][L][192]  @ 524288   (786432)

typedef float v2f __attribute__((ext_vector_type(2)));
typedef float v4f __attribute__((ext_vector_type(4)));

// ---------------------------------------------------------------------------
// Kernel 1: key_emb -> q, k projections. One thread per (b,l).
// ---------------------------------------------------------------------------
__global__ __launch_bounds__(256) void k_embed(
    const float* __restrict__ ts, const float* __restrict__ Wl,
    const float* __restrict__ bl, const float* __restrict__ Wp,
    const float* __restrict__ bp, const float* __restrict__ Wq,
    const float* __restrict__ bq, const float* __restrict__ Wk,
    const float* __restrict__ bk,
    float* __restrict__ qmat, float* __restrict__ kmatT)
{
    __shared__ float WqL[1024], WkL[1024];
    __shared__ float bqL[32], bkL[32], WpL[31], bpL[31];
    __shared__ float wl0, bl0;
    const int tid = threadIdx.x;

    {
        float4 v = ((const float4*)Wq)[tid];
        ((float4*)WqL)[tid] = v;
        float4 u = ((const float4*)Wk)[tid];
        ((float4*)WkL)[tid] = u;
    }
    if (tid < 32) { bqL[tid] = bq[tid]; bkL[tid] = bk[tid]; }
    if (tid < 31) { WpL[tid] = Wp[tid]; bpL[tid] = bp[tid]; }
    if (tid == 0) { wl0 = Wl[0]; bl0 = bl[0]; }
    __syncthreads();

    const int p = blockIdx.x * 256 + tid;      // 0..4095
    const float t = ts[p];
    float e[32];
    e[0] = t * wl0 + bl0;
    #pragma unroll
    for (int j = 1; j < 32; ++j) e[j] = sinf(t * WpL[j - 1] + bpL[j - 1]);

    const int b = p >> 9, l = p & 511;
    float4* qm4 = (float4*)(qmat + (size_t)p * 32);
    float*  kT  = kmatT + (size_t)b * 32 * 512 + l;

    for (int dq = 0; dq < 8; ++dq) {
        float q0 = bqL[4*dq+0], q1 = bqL[4*dq+1], q2 = bqL[4*dq+2], q3 = bqL[4*dq+3];
        float k0 = bkL[4*dq+0], k1 = bkL[4*dq+1], k2 = bkL[4*dq+2], k3 = bkL[4*dq+3];
        const float* wq = &WqL[(4*dq) * 32];
        const float* wk = &WkL[(4*dq) * 32];
        #pragma unroll
        for (int j = 0; j < 32; ++j) {
            const float ej = e[j];
            q0 = fmaf(wq[j],      ej, q0);
            q1 = fmaf(wq[32 + j], ej, q1);
            q2 = fmaf(wq[64 + j], ej, q2);
            q3 = fmaf(wq[96 + j], ej, q3);
            k0 = fmaf(wk[j],      ej, k0);
            k1 = fmaf(wk[32 + j], ej, k1);
            k2 = fmaf(wk[64 + j], ej, k2);
            k3 = fmaf(wk[96 + j], ej, k3);
        }
        qm4[dq] = make_float4(q0, q1, q2, q3);
        kT[(4*dq + 0) * 512] = k0;
        kT[(4*dq + 1) * 512] = k1;
        kT[(4*dq + 2) * 512] = k2;
        kT[(4*dq + 3) * 512] = k3;
    }
}

// ---------------------------------------------------------------------------
// Kernel 2 (FUSED attn + gi): per-(b,qb) attention -> att rows in LDS ->
// gi = att @ W_ih^T + b_ih written directly.  grid (32 qb, 8 b), 256 thr.
// (r7-verified: fusion saved ~55 us of residue; bit-exact vs unfused.)
// ---------------------------------------------------------------------------
__global__ __launch_bounds__(256) void k_attn_gi(
    const float* __restrict__ qmat, const float* __restrict__ kmatT,
    const float* __restrict__ val,  const int*   __restrict__ mark,
    const float* __restrict__ npm,  const float* __restrict__ Wo,
    const float* __restrict__ bo,   const float* __restrict__ Wih,
    const float* __restrict__ bih,  float* __restrict__ gi)
{
    __shared__ float srow[4 * 512];   // per-wave score row
    __shared__ int   cc[512];         // category (-1 if padded)
    __shared__ float vv[512];         // values
    __shared__ float WL[192 * 65];    // W_ih staged (padded rows)
    __shared__ float bL[192];
    __shared__ float attL[16 * 64];   // the 16 att rows this block owns
    const int tid = threadIdx.x;
    const int qb  = blockIdx.x;       // 0..31
    const int b   = blockIdx.y;       // 0..7

    for (int k = tid; k < 512; k += 256) {
        const int   m  = mark[b * 512 + k];
        const float np = npm[b * 512 + k];
        cc[k] = (np > 0.0f) ? (m - 1) : -1;
        vv[k] = val[b * 512 + k];
    }
    // stage W_ih (verbatim from old k_gi)
    for (int idx = tid; idx < 3072; idx += 256) {
        float4 v = ((const float4*)Wih)[idx];
        const int g = idx >> 4, jq = idx & 15;
        float* dst = &WL[g * 65 + jq * 4];
        dst[0] = v.x; dst[1] = v.y; dst[2] = v.z; dst[3] = v.w;
    }
    if (tid < 192) bL[tid] = bih[tid];
    __syncthreads();

    const int w = tid >> 6, lane = tid & 63;
    const float* kTb = kmatT + (size_t)b * 32 * 512;

    for (int iq = 0; iq < 4; ++iq) {
        const int q = qb * 16 + w * 4 + iq;

        float qr[32];
        const float4* qm4 = (const float4*)(qmat + (size_t)(b * 512 + q) * 32);
        #pragma unroll
        for (int j4 = 0; j4 < 8; ++j4) {
            float4 v = qm4[j4];
            qr[4*j4+0] = v.x; qr[4*j4+1] = v.y; qr[4*j4+2] = v.z; qr[4*j4+3] = v.w;
        }

        float acc[8];
        #pragma unroll
        for (int m = 0; m < 8; ++m) acc[m] = 0.0f;
        #pragma unroll 4
        for (int j = 0; j < 32; ++j) {
            const float* row = kTb + j * 512 + lane;
            const float  qj  = qr[j];
            #pragma unroll
            for (int m = 0; m < 8; ++m) acc[m] = fmaf(qj, row[m * 64], acc[m]);
        }
        #pragma unroll
        for (int m = 0; m < 8; ++m)
            srow[w * 512 + m * 64 + lane] = acc[m] * 0.17677669529663687f;
        __syncthreads();

        const int c = lane & 15, s = lane >> 4;
        float mx = -1e30f, Z = 0.0f, X = 0.0f;
        const int base = s * 128;
        for (int t = 0; t < 128; ++t) {
            const int k = base + ((t + s) & 127);
            if (cc[k] == c) {
                const float l  = (k <= q + WOFF_) ? srow[w * 512 + k] : 0.0f;
                const float mn = fmaxf(mx, l);
                const float e1 = __expf(l - mn);
                const float sc = __expf(mx - mn);
                Z = Z * sc + e1;
                X = X * sc + e1 * vv[k];
                mx = mn;
            }
        }
        #pragma unroll
        for (int off = 16; off <= 32; off <<= 1) {
            const float mo = __shfl_xor(mx, off);
            const float Zo = __shfl_xor(Z, off);
            const float Xo = __shfl_xor(X, off);
            const float mn = fmaxf(mx, mo);
            const float a0 = __expf(mx - mn);
            const float a1 = __expf(mo - mn);
            Z = Z * a0 + Zo * a1;
            X = X * a0 + Xo * a1;
            mx = mn;
        }
        const float x = (Z > 0.0f) ? X / Z : 0.0f;

        float xs[16];
        #pragma unroll
        for (int c2 = 0; c2 < 16; ++c2) xs[c2] = __shfl(x, c2);

        const float4* wo4 = (const float4*)(Wo + lane * 16);
        float a = bo[lane];
        #pragma unroll
        for (int c4 = 0; c4 < 4; ++c4) {
            float4 v = wo4[c4];
            a += xs[4*c4+0] * v.x + xs[4*c4+1] * v.y + xs[4*c4+2] * v.z + xs[4*c4+3] * v.w;
        }
        attL[(w * 4 + iq) * 64 + lane] = a;   // row stays in LDS
        __syncthreads();
    }
    // final barrier of the iq loop makes all 16 attL rows visible

    // ---- gi part (verbatim from old k_gi; arow reads attL) ----
    const size_t out0 = (size_t)(b * 32 + qb) * 16 * 192;
    for (int pp = 0; pp < 12; ++pp) {
        const int p = tid + 256 * pp;
        const int r = p / 192, g = p - r * 192;
        float a0 = bL[g], a1 = 0.f, a2 = 0.f, a3 = 0.f;
        const float* wrow = &WL[g * 65];
        const float* arow = &attL[r * 64];
        #pragma unroll
        for (int j = 0; j < 64; j += 4) {
            a0 = fmaf(arow[j + 0], wrow[j + 0], a0);
            a1 = fmaf(arow[j + 1], wrow[j + 1], a1);
            a2 = fmaf(arow[j + 2], wrow[j + 2], a2);
            a3 = fmaf(arow[j + 3], wrow[j + 3], a3);
        }
        gi[out0 + p] = (a0 + a1) + (a2 + a3);
    }
}

// ---------------------------------------------------------------------------
// Kernel 4: sequential GRU — r6 form restored: one wave per batch, one
// block per CU (<<<8,64>>>), LDS h-broadcast, no barrier, 2-deep gi ring,
// register-pressure-fitted issue stream.
//
// r7 post-mortem: 8 waves on ONE CU (2/SIMD) regressed 175->286 us.
// Co-residency arithmetic: per-wave issue ~500 cy > per-wave stall ~320 cy,
// so sharing a SIMD serializes the dominant term (2x500 issue + residual
// stall = ~1340 cy/pair vs 819 alone). Multi-wave hiding only pays when
// stall > issue. 8 blocks on 8 CUs (each wave alone on its SIMD) is the
// right placement for this issue-heavy recurrence.
// ---------------------------------------------------------------------------

#define GRU_STEP(u, DO_REFILL) {                                           \
    v4f hv[16];                                                            \
    /* prologue: issue 6 chunks ahead */                                   \
    _Pragma("unroll")                                                      \
    for (int k = 0; k < 6; ++k) hv[k] = hs4[k];                            \
    const float gr = pr[u], gz = pz[u], gn = pn[u];                        \
    if (DO_REFILL) {                                                       \
        pr[u] = pf[0];                                                     \
        pz[u] = pf[64];                                                    \
        pn[u] = pf[128];                                                   \
        pf += 192;                                                         \
    }                                                                      \
    v2f ar2 = {gr + br, 0.0f};                                             \
    v2f az2 = {gz + bz, 0.0f};                                             \
    v2f an2 = {bn, 0.0f};                                                  \
    _Pragma("unroll")                                                      \
    for (int k = 0; k < 16; ++k) {                                         \
        if (k < 10) hv[k + 6] = hs4[k + 6];   /* stay 6 ahead */           \
        v2f p0 = __builtin_shufflevector(hv[k], hv[k], 0, 1);              \
        v2f p1 = __builtin_shufflevector(hv[k], hv[k], 2, 3);              \
        ar2 = wr[2*k]     * p0 + ar2;   /* v_pk_fma_f32 */                 \
        az2 = wz[2*k]     * p0 + az2;                                      \
        an2 = wn[2*k]     * p0 + an2;                                      \
        ar2 = wr[2*k + 1] * p1 + ar2;                                      \
        az2 = wz[2*k + 1] * p1 + az2;                                      \
        an2 = wn[2*k + 1] * p1 + an2;                                      \
    }                                                                      \
    const float ar = ar2.x + ar2.y;                                        \
    const float az = az2.x + az2.y;                                        \
    const float hn = an2.x + an2.y;                                        \
    const float r = __builtin_amdgcn_rcpf(1.0f + __expf(-ar));             \
    const float z = __builtin_amdgcn_rcpf(1.0f + __expf(-az));             \
    float npre = gn + r * hn;                                              \
    npre = fminf(fmaxf(npre, -15.0f), 15.0f);                              \
    const float e2 = __expf(2.0f * npre);                                  \
    const float n  = (e2 - 1.0f) * __builtin_amdgcn_rcpf(e2 + 1.0f);       \
    h = fmaf(z, h - n, n);            /* (1-z)*n + z*h */                  \
    hs[lane] = h;                     /* next step's broadcast source */   \
    *outp = h;                        /* fire-and-forget */                \
    outp += 64;                                                            \
}

__global__ __launch_bounds__(64, 1) void k_gru(
    const float* __restrict__ gi, const float* __restrict__ Whh,
    const float* __restrict__ bhh, float* __restrict__ out)
{
    __shared__ float hs[64];
    const int lane = threadIdx.x;     // 0..63
    const int b    = blockIdx.x;      // 0..7

    // Stage this lane's three W_hh rows into registers (as 32 x v2f each).
    v2f wr[32], wz[32], wn[32];
    {
        const v2f* r2 = (const v2f*)(Whh + (size_t)lane * 64);
        const v2f* z2 = (const v2f*)(Whh + (size_t)(lane + 64) * 64);
        const v2f* n2 = (const v2f*)(Whh + (size_t)(lane + 128) * 64);
        #pragma unroll
        for (int j = 0; j < 32; ++j) {
            wr[j] = r2[j];
            wz[j] = z2[j];
            wn[j] = n2[j];
        }
    }
    const float br = bhh[lane];
    const float bz = bhh[lane + 64];
    const float bn = bhh[lane + 128];

    const float* gib  = gi  + (size_t)b * 512 * 192;
    float*       outp = out + (size_t)b * 512 * 64 + lane;

    float h = 0.0f;
    hs[lane] = 0.0f;                  // h_{-1} = 0 (same wave; DS in-order)

    // 2-deep gi prefetch ring
    float pr[2], pz[2], pn[2];
    #pragma unroll
    for (int i = 0; i < 2; ++i) {
        const float* gp = gib + (size_t)i * 192;
        pr[i] = gp[lane];
        pz[i] = gp[lane + 64];
        pn[i] = gp[lane + 128];
    }
    // refill pointer: lane offset baked in, advanced +192 per step
    const float* pf = gib + (size_t)2 * 192 + lane;

    const v4f* hs4 = (const v4f*)hs;

    // main loop: 255 groups of 2, steps 0..509, refills rows 2..511
    for (int tt = 0; tt < 510; tt += 2) {
        GRU_STEP(0, 1)
        GRU_STEP(1, 1)
    }
    // epilogue: steps 510..511 from the ring, no refill
    GRU_STEP(0, 0)
    GRU_STEP(1, 0)
}

// ---------------------------------------------------------------------------
extern "C" void kernel_launch(void* const* d_in, const int* in_sizes, int n_in,
                              void* d_out, int out_size, void* d_ws, size_t ws_size,
                              hipStream_t stream)
{
    const float* ts   = (const float*)d_in[0];
    const float* val  = (const float*)d_in[1];
    const int*   mark = (const int*)  d_in[2];
    const float* npm  = (const float*)d_in[3];
    const float* Wl   = (const float*)d_in[4];
    const float* bl   = (const float*)d_in[5];
    const float* Wp   = (const float*)d_in[6];
    const float* bp   = (const float*)d_in[7];
    const float* Wq   = (const float*)d_in[8];
    const float* bq   = (const float*)d_in[9];
    const float* Wk   = (const float*)d_in[10];
    const float* bk   = (const float*)d_in[11];
    const float* Wo   = (const float*)d_in[12];
    const float* bo   = (const float*)d_in[13];
    const float* Wih  = (const float*)d_in[14];
    const float* Whh  = (const float*)d_in[15];
    const float* bih  = (const float*)d_in[16];
    const float* bhh  = (const float*)d_in[17];

    float* ws    = (float*)d_ws;
    float* qmat  = ws;                 // 131072
    float* kmatT = ws + 131072;        // 131072
    float* gi    = ws + 524288;        // 786432
    float* out   = (float*)d_out;

    k_embed<<<16, 256, 0, stream>>>(ts, Wl, bl, Wp, bp, Wq, bq, Wk, bk, qmat, kmatT);
    k_attn_gi<<<dim3(32, 8), 256, 0, stream>>>(qmat, kmatT, val, mark, npm, Wo, bo, Wih, bih, gi);
    k_gru<<<8, 64, 0, stream>>>(gi, Whh, bhh, out);
}